// Round 6
// baseline (223.866 us; speedup 1.0000x reference)
//
#include <hip/hip_runtime.h>
#include <stdint.h>

// Problem constants
#define LDIM 256
#define CDIM 20
#define LC   5120      // L*C
#define NB   1024      // batch
#define BM   128       // i-tile rows
#define BN   256       // batch tile
#define ITOT64 1640    // sum_it (80 - 2*it): 64-K iters per b-col
// exact identities: kstart(it) = 128*it = i0 ; iters64(it) = 80 - 2*it

typedef __attribute__((ext_vector_type(8))) short short8;       // 8 bf16 (4 VGPR)
typedef __attribute__((ext_vector_type(4))) float float4v;      // MFMA acc
typedef __attribute__((ext_vector_type(4))) unsigned int uint4v;
typedef unsigned short ushort_t;

#define TB_BYTES (52428800ull)            // 5120*5120*2
#define XB_BYTES (10485760ull)            // 1024*5120*2
#define WS_NEED  (TB_BYTES + XB_BYTES)

// round-to-nearest-even fp32 -> bf16, packed pair
__device__ inline uint32_t pack_bf16x2(float a, float b) {
    uint32_t ua = __float_as_uint(a);
    uint32_t ub = __float_as_uint(b);
    ua += 0x7fffu + ((ua >> 16) & 1u);
    ub += 0x7fffu + ((ub >> 16) & 1u);
    return (ua >> 16) | (ub & 0xffff0000u);
}

__device__ inline float bf16_to_f32(ushort_t u) {
    return __uint_as_float(((uint32_t)u) << 16);
}

// async global->LDS 16B; lds base wave-uniform (HW: base + lane*16)
// aux = cpol: 0 = cached normally (X: keep L2-resident), 2 = NT streaming
// (T: evict-first, don't thrash the X slab out of the XCD L2)
__device__ inline void load_lds16(const void* g, void* l) {
    __builtin_amdgcn_global_load_lds(
        (const __attribute__((address_space(1))) uint32_t*)g,
        (__attribute__((address_space(3))) uint32_t*)l, 16, 0, 0);
}
__device__ inline void load_lds16_nt(const void* g, void* l) {
    __builtin_amdgcn_global_load_lds(
        (const __attribute__((address_space(1))) uint32_t*)g,
        (__attribute__((address_space(3))) uint32_t*)l, 16, 0, 2);
}

// ---------------------------------------------------------------------------
// Convert pass: T fp32 -> bf16 (cols >= 128*(row>>7) only), X fp32 -> bf16,
// fused out[b] = theta0 + dot(theta_lc, x[b,:]).
// ---------------------------------------------------------------------------
__global__ __launch_bounds__(256) void conv_kernel(
    const float* __restrict__ T, const float* __restrict__ X,
    const float* __restrict__ th0, const float* __restrict__ thlc,
    ushort_t* __restrict__ Tb, ushort_t* __restrict__ Xb,
    float* __restrict__ out)
{
    const int bid = blockIdx.x;
    const int t   = threadIdx.x;
    __shared__ float red[4];

    if (bid < LC) {
        const int r  = bid;
        const int tk = (r >> 7) << 7;      // tile kstart (exact identity)
        const float*  src = T  + (size_t)r * LC;
        ushort_t*     dst = Tb + (size_t)r * LC;
        for (int c = tk + t * 4; c < LC; c += 1024) {
            float4 f = *(const float4*)(src + c);
            uint2 u;
            u.x = pack_bf16x2(f.x, f.y);
            u.y = pack_bf16x2(f.z, f.w);
            *(uint2*)(dst + c) = u;
        }
    } else {
        const int b = bid - LC;
        const float*  src = X  + (size_t)b * LC;
        ushort_t*     dst = Xb + (size_t)b * LC;
        float s = 0.f;
        for (int c = t * 4; c < LC; c += 1024) {
            float4 f = *(const float4*)(src + c);
            float4 w = *(const float4*)(thlc + c);
            s += f.x * w.x + f.y * w.y + f.z * w.z + f.w * w.w;
            uint2 u;
            u.x = pack_bf16x2(f.x, f.y);
            u.y = pack_bf16x2(f.z, f.w);
            *(uint2*)(dst + c) = u;
        }
        s += __shfl_xor(s, 1);  s += __shfl_xor(s, 2);  s += __shfl_xor(s, 4);
        s += __shfl_xor(s, 8);  s += __shfl_xor(s, 16); s += __shfl_xor(s, 32);
        if ((t & 63) == 0) red[t >> 6] = s;
        __syncthreads();
        if (t == 0) out[b] = th0[0] + red[0] + red[1] + red[2] + red[3];
    }
}

// ---------------------------------------------------------------------------
// Pair kernel v5: v4 structure + cache-tier control.
//   decode: xcd = n&7 ; bcol = xcd&3 (one X slab, 2.6 MB, per XCD -> L2-
//   resident) ; kblk = 2*(n>>3) + (xcd>>2) (even/odd kblks on the two XCDs
//   sharing a bcol). T staged with NT (evict-first) so the 13 MB/XCD T
//   stream does not evict the X slab.
// ---------------------------------------------------------------------------
__global__ __launch_bounds__(256, 2) void pair_bf(
    const ushort_t* __restrict__ Tb, const ushort_t* __restrict__ Xb,
    float* __restrict__ out)
{
    const int n    = blockIdx.x;
    const int xcd  = n & 7;                  // XCD id under n%8 round-robin
    const int bn0  = (xcd & 3) * BN;         // one bcol per XCD
    const int kblk = ((n >> 3) << 1) | (xcd >> 2);   // 0..127, unique per (kblk,bcol)

    const int gbeg = (ITOT64 * kblk) >> 7;
    const int gend = (ITOT64 * (kblk + 1)) >> 7;

    // locate starting segment
    int it = 0, pre = 0;
    while (pre + (80 - 2 * it) <= gbeg) { pre += 80 - 2 * it; ++it; }
    int li = gbeg - pre;

    // LDS: chunk(row, slot) = row*8 + slot, 16 B/chunk; slot = g ^ (row&7)
    __shared__ __align__(16) ushort_t A_s[1024 * 8];   // 16 KB (128 rows x 8 granules)
    __shared__ __align__(16) ushort_t B_s[2048 * 8];   // 32 KB (256 rows x 8 granules)

    const int t    = threadIdx.x;
    const int lane = t & 63;
    const int wid  = t >> 6;
    const int wm   = (wid >> 1) * 64;        // wave i-offset
    const int wn   = (wid & 1) * 128;        // wave b-offset
    const int l16  = lane & 15;
    const int qk   = lane >> 4;              // k-quad within a 32-K MFMA step

    // ---- DMA lane constants (8 lanes/row: each 16-lane phase = 2 full lines)
    uint32_t offA[4];
    #pragma unroll
    for (int j = 0; j < 4; ++j) {
        const int c = (wid << 8) + (j << 6) + lane;
        const int row = c >> 3;
        const int g = (c & 7) ^ (row & 7);
        offA[j] = (uint32_t)row * LC + (g << 3);
    }
    uint32_t offB[8];
    #pragma unroll
    for (int j = 0; j < 8; ++j) {
        const int c = (wid << 9) + (j << 6) + lane;
        const int row = c >> 3;
        const int g = (c & 7) ^ (row & 7);
        offB[j] = (uint32_t)(bn0 + row) * LC + (g << 3);
    }

    // ---- LDS fragment read byte-addresses (loop-invariant)
    int adrA[2][4], adrB[2][8];
    #pragma unroll
    for (int step = 0; step < 2; ++step) {
        const int kf = step * 4 + qk;        // granule 0..7
        #pragma unroll
        for (int mt = 0; mt < 4; ++mt) {
            const int r = wm + mt * 16 + l16;
            adrA[step][mt] = ((r << 3) + (kf ^ (r & 7))) << 4;
        }
        #pragma unroll
        for (int nt = 0; nt < 8; ++nt) {
            const int r = wn + nt * 16 + l16;
            adrB[step][nt] = ((r << 3) + (kf ^ (r & 7))) << 4;
        }
    }

    int   i0    = it << 7;
    int   k0    = i0 + (li << 6);            // kstart + li*64
    size_t baseA = (size_t)i0 * LC + k0;

    float4v acc[4][8];
    #pragma unroll
    for (int mt = 0; mt < 4; ++mt)
        #pragma unroll
        for (int nt = 0; nt < 8; ++nt)
            #pragma unroll
            for (int r = 0; r < 4; ++r) acc[mt][nt][r] = 0.f;

    for (int g = gbeg; g < gend; ++g) {
        __syncthreads();                     // prior fragment reads done
        #pragma unroll
        for (int j = 0; j < 4; ++j)          // T: NT streaming (protect L2)
            load_lds16_nt(Tb + baseA + offA[j], A_s + (((wid << 8) + (j << 6)) << 3));
        #pragma unroll
        for (int j = 0; j < 8; ++j)          // X: normal (L2-resident slab)
            load_lds16(Xb + k0 + offB[j],   B_s + (((wid << 9) + (j << 6)) << 3));
        __syncthreads();                     // DMA drained (vmcnt 0 at barrier)

        #pragma unroll
        for (int step = 0; step < 2; ++step) {
            short8 af[4], bfr[8];
            #pragma unroll
            for (int mt = 0; mt < 4; ++mt)
                af[mt] = *(const short8*)((const char*)A_s + adrA[step][mt]);
            #pragma unroll
            for (int nt = 0; nt < 8; ++nt)
                bfr[nt] = *(const short8*)((const char*)B_s + adrB[step][nt]);
            #pragma unroll
            for (int mt = 0; mt < 4; ++mt)
                #pragma unroll
                for (int nt = 0; nt < 8; ++nt)
                    acc[mt][nt] = __builtin_amdgcn_mfma_f32_16x16x32_bf16(
                        af[mt], bfr[nt], acc[mt][nt], 0, 0, 0);
        }

        ++li;
        const bool segEnd = (li == 80 - 2 * it);
        if (segEnd || g + 1 == gend) {
            // epilogue flush: out[b] += sum_i x[b,i] * D[i,b], x from bf16 Xb
            #pragma unroll
            for (int nt = 0; nt < 8; ++nt) {
                const int b = bn0 + wn + nt * 16 + l16;
                const ushort_t* xb = Xb + (size_t)b * LC + i0 + wm + qk * 4;
                float s = 0.f;
                #pragma unroll
                for (int mt = 0; mt < 4; ++mt) {
                    ushort4 xv = *(const ushort4*)(xb + mt * 16);
                    s += acc[mt][nt][0] * bf16_to_f32(xv.x)
                       + acc[mt][nt][1] * bf16_to_f32(xv.y)
                       + acc[mt][nt][2] * bf16_to_f32(xv.z)
                       + acc[mt][nt][3] * bf16_to_f32(xv.w);
                }
                s += __shfl_xor(s, 16);      // reduce the 4 k-quads (same b)
                s += __shfl_xor(s, 32);
                if (qk == 0) atomicAdd(&out[b], s);
            }
            #pragma unroll
            for (int mt = 0; mt < 4; ++mt)
                #pragma unroll
                for (int nt = 0; nt < 8; ++nt)
                    #pragma unroll
                    for (int r = 0; r < 4; ++r) acc[mt][nt][r] = 0.f;
        }
        if (segEnd) {
            ++it; li = 0;
            if (it < 40) {
                i0 = it << 7;
                k0 = i0;
                baseA = (size_t)i0 * LC + k0;
            }
        } else {
            k0 += 64;
            baseA += 64;
        }
    }
}

// ===========================================================================
// Fallback (ws too small): proven R2 path, fp32 staging from global.
// ===========================================================================
__global__ __launch_bounds__(256) void init_kernel(
    const float* __restrict__ x, const float* __restrict__ th0,
    const float* __restrict__ thlc, float* __restrict__ out)
{
    const int b = blockIdx.x;
    const float4* xb = (const float4*)(x + (size_t)b * LC);
    const float4* tv = (const float4*)thlc;
    float s = 0.f;
    for (int i = threadIdx.x; i < LC / 4; i += 256) {
        float4 a = xb[i], t = tv[i];
        s += a.x * t.x + a.y * t.y + a.z * t.z + a.w * t.w;
    }
    s += __shfl_xor(s, 1);  s += __shfl_xor(s, 2);  s += __shfl_xor(s, 4);
    s += __shfl_xor(s, 8);  s += __shfl_xor(s, 16); s += __shfl_xor(s, 32);
    __shared__ float red[4];
    if ((threadIdx.x & 63) == 0) red[threadIdx.x >> 6] = s;
    __syncthreads();
    if (threadIdx.x == 0) out[b] = th0[0] + red[0] + red[1] + red[2] + red[3];
}

__global__ __launch_bounds__(256) void pair_kernel(
    const float* __restrict__ T, const float* __restrict__ X,
    float* __restrict__ out)
{
    const int n  = blockIdx.x;
    const int r  = n & 7;
    const int g  = n >> 3;
    const int i0  = (g >> 3) * BM;
    const int bn0 = (g & 7) * 128;
    const int kstart = i0;
    const int nIter  = (LC - kstart) >> 6;
    const int ipc    = (nIter + 7) >> 3;
    const int itBeg  = r * ipc;
    const int itEnd  = (itBeg + ipc < nIter) ? (itBeg + ipc) : nIter;
    if (itBeg >= itEnd) return;
    const int kbeg   = kstart + (itBeg << 6);

    __shared__ __align__(16) short A_s[8 * BM * 8];
    __shared__ __align__(16) short B_s[8 * BM * 8];

    const int t    = threadIdx.x;
    const int lane = t & 63;
    const int wid  = t >> 6;
    const int wm   = (wid >> 1) * 64;
    const int wn   = (wid & 1) * 64;
    const int l16  = lane & 15;
    const int qk   = lane >> 4;

    const float* pA[4]; const float* pB[4]; int sIdx[4];
    #pragma unroll
    for (int u = 0; u < 4; ++u) {
        const int id  = t + u * 256;
        const int row = id >> 3;
        const int kq  = id & 7;
        pA[u] = T + (size_t)(i0 + row) * LC + kbeg + kq * 8;
        pB[u] = X + (size_t)(bn0 + row) * LC + kbeg + kq * 8;
        sIdx[u] = (kq * BM + (row ^ kq)) * 8;
    }

    float4v acc[4][4] = {};
    for (int itr = itBeg; itr < itEnd; ++itr) {
        __syncthreads();
        #pragma unroll
        for (int u = 0; u < 4; ++u) {
            float4 a0 = ((const float4*)pA[u])[0];
            float4 a1 = ((const float4*)pA[u])[1];
            float4 b0 = ((const float4*)pB[u])[0];
            float4 b1 = ((const float4*)pB[u])[1];
            pA[u] += 64; pB[u] += 64;
            uint4v va, vb;
            va[0] = pack_bf16x2(a0.x, a0.y); va[1] = pack_bf16x2(a0.z, a0.w);
            va[2] = pack_bf16x2(a1.x, a1.y); va[3] = pack_bf16x2(a1.z, a1.w);
            vb[0] = pack_bf16x2(b0.x, b0.y); vb[1] = pack_bf16x2(b0.z, b0.w);
            vb[2] = pack_bf16x2(b1.x, b1.y); vb[3] = pack_bf16x2(b1.z, b1.w);
            *(uint4v*)(A_s + sIdx[u]) = va;
            *(uint4v*)(B_s + sIdx[u]) = vb;
        }
        __syncthreads();
        #pragma unroll
        for (int step = 0; step < 2; ++step) {
            const int kf = step * 4 + qk;
            short8 af[4], bfr[4];
            #pragma unroll
            for (int mt = 0; mt < 4; ++mt)
                af[mt] = *(const short8*)(A_s + (kf * BM + ((wm + mt * 16 + l16) ^ kf)) * 8);
            #pragma unroll
            for (int nt = 0; nt < 4; ++nt)
                bfr[nt] = *(const short8*)(B_s + (kf * BM + ((wn + nt * 16 + l16) ^ kf)) * 8);
            #pragma unroll
            for (int mt = 0; mt < 4; ++mt)
                #pragma unroll
                for (int nt = 0; nt < 4; ++nt)
                    acc[mt][nt] = __builtin_amdgcn_mfma_f32_16x16x32_bf16(
                        af[mt], bfr[nt], acc[mt][nt], 0, 0, 0);
        }
    }
    #pragma unroll
    for (int nt = 0; nt < 4; ++nt) {
        const int b = bn0 + wn + nt * 16 + l16;
        const float* xb = X + (size_t)b * LC + i0 + wm + qk * 4;
        float s = 0.f;
        #pragma unroll
        for (int mt = 0; mt < 4; ++mt) {
            float4 xv = *(const float4*)(xb + mt * 16);
            s += acc[mt][nt][0] * xv.x + acc[mt][nt][1] * xv.y +
                 acc[mt][nt][2] * xv.z + acc[mt][nt][3] * xv.w;
        }
        s += __shfl_xor(s, 16);
        s += __shfl_xor(s, 32);
        if (qk == 0) atomicAdd(&out[b], s);
    }
}

extern "C" void kernel_launch(void* const* d_in, const int* in_sizes, int n_in,
                              void* d_out, int out_size, void* d_ws, size_t ws_size,
                              hipStream_t stream) {
    const float* x    = (const float*)d_in[0];   // (B, L, C) fp32
    const float* th0  = (const float*)d_in[1];   // (1,)
    const float* thlc = (const float*)d_in[2];   // (1, L, C)
    const float* T    = (const float*)d_in[3];   // (1, L, C, L, C) — pre-masked
    float* out = (float*)d_out;                  // (B, 1) fp32

    if (ws_size >= WS_NEED) {
        ushort_t* Tb = (ushort_t*)d_ws;
        ushort_t* Xb = (ushort_t*)((char*)d_ws + TB_BYTES);
        conv_kernel<<<LC + NB, 256, 0, stream>>>(T, x, th0, thlc, Tb, Xb, out);
        pair_bf<<<512, 256, 0, stream>>>(Tb, Xb, out);
    } else {
        init_kernel<<<NB, 256, 0, stream>>>(x, th0, thlc, out);
        pair_kernel<<<(LC / BM) * (NB / 128) * 8, 256, 0, stream>>>(T, x, out);
    }
}

// Round 7
// 221.499 us; speedup vs baseline: 1.0107x; 1.0107x over previous
//
#include <hip/hip_runtime.h>
#include <stdint.h>

// Problem constants
#define LDIM 256
#define CDIM 20
#define LC   5120      // L*C
#define NB   1024      // batch
#define BM   256       // i-tile rows (v6: doubled to halve X re-staging)
#define BN   256       // batch tile
#define ITOT64 840     // sum_it (80 - 4*it), it=0..19 : 64-K iters per b-col
// exact identities (BM=256): kstart(it) = 256*it = i0 ; iters64(it) = 80 - 4*it

typedef __attribute__((ext_vector_type(8))) short short8;       // 8 bf16 (4 VGPR)
typedef __attribute__((ext_vector_type(4))) float float4v;      // MFMA acc
typedef __attribute__((ext_vector_type(4))) unsigned int uint4v;
typedef unsigned short ushort_t;

#define TB_BYTES (52428800ull)            // 5120*5120*2
#define XB_BYTES (10485760ull)            // 1024*5120*2
#define WS_NEED  (TB_BYTES + XB_BYTES)

// round-to-nearest-even fp32 -> bf16, packed pair
__device__ inline uint32_t pack_bf16x2(float a, float b) {
    uint32_t ua = __float_as_uint(a);
    uint32_t ub = __float_as_uint(b);
    ua += 0x7fffu + ((ua >> 16) & 1u);
    ub += 0x7fffu + ((ub >> 16) & 1u);
    return (ua >> 16) | (ub & 0xffff0000u);
}

__device__ inline float bf16_to_f32(ushort_t u) {
    return __uint_as_float(((uint32_t)u) << 16);
}

// async global->LDS 16B; lds base wave-uniform (HW: base + lane*16). No cpol
// games: R6 showed aux=2 (NT) wrecks staging BW (sub-line/non-allocating).
__device__ inline void load_lds16(const void* g, void* l) {
    __builtin_amdgcn_global_load_lds(
        (const __attribute__((address_space(1))) uint32_t*)g,
        (__attribute__((address_space(3))) uint32_t*)l, 16, 0, 0);
}

// ---------------------------------------------------------------------------
// Convert pass: T fp32 -> bf16 (cols >= 128*(row>>7) only — superset of the
// BM=256 need), X fp32 -> bf16, fused out[b] = theta0 + dot(theta_lc, x[b,:]).
// ---------------------------------------------------------------------------
__global__ __launch_bounds__(256) void conv_kernel(
    const float* __restrict__ T, const float* __restrict__ X,
    const float* __restrict__ th0, const float* __restrict__ thlc,
    ushort_t* __restrict__ Tb, ushort_t* __restrict__ Xb,
    float* __restrict__ out)
{
    const int bid = blockIdx.x;
    const int t   = threadIdx.x;
    __shared__ float red[4];

    if (bid < LC) {
        const int r  = bid;
        const int tk = (r >> 8) << 8;      // BM=256 tile kstart (exact identity)
        const float*  src = T  + (size_t)r * LC;
        ushort_t*     dst = Tb + (size_t)r * LC;
        for (int c = tk + t * 4; c < LC; c += 1024) {
            float4 f = *(const float4*)(src + c);
            uint2 u;
            u.x = pack_bf16x2(f.x, f.y);
            u.y = pack_bf16x2(f.z, f.w);
            *(uint2*)(dst + c) = u;
        }
    } else {
        const int b = bid - LC;
        const float*  src = X  + (size_t)b * LC;
        ushort_t*     dst = Xb + (size_t)b * LC;
        float s = 0.f;
        for (int c = t * 4; c < LC; c += 1024) {
            float4 f = *(const float4*)(src + c);
            float4 w = *(const float4*)(thlc + c);
            s += f.x * w.x + f.y * w.y + f.z * w.z + f.w * w.w;
            uint2 u;
            u.x = pack_bf16x2(f.x, f.y);
            u.y = pack_bf16x2(f.z, f.w);
            *(uint2*)(dst + c) = u;
        }
        s += __shfl_xor(s, 1);  s += __shfl_xor(s, 2);  s += __shfl_xor(s, 4);
        s += __shfl_xor(s, 8);  s += __shfl_xor(s, 16); s += __shfl_xor(s, 32);
        if ((t & 63) == 0) red[t >> 6] = s;
        __syncthreads();
        if (t == 0) out[b] = th0[0] + red[0] + red[1] + red[2] + red[3];
    }
}

// ---------------------------------------------------------------------------
// Pair kernel v6: 256x256 tile, 512 threads (8 waves, 64x128 per wave),
// BK=64 single-buffer LDS (64 KB), full-line DMA, R5-proven decode
// (same-kblk bcol-siblings adjacent & same XCD mod 8). 256 blocks, 1/CU.
// Staged bytes: 215 MB (was 315 with BM=128).
// ---------------------------------------------------------------------------
__global__ __launch_bounds__(512, 2) void pair_bf(
    const ushort_t* __restrict__ Tb, const ushort_t* __restrict__ Xb,
    float* __restrict__ out)
{
    const int n    = blockIdx.x;                   // 0..255
    const int kblk = (n & 7) | ((n >> 5) << 3);    // 0..63; siblings n,n+8,n+16,n+24
    const int bn0  = ((n >> 3) & 3) * BN;

    const int gbeg = (ITOT64 * kblk) >> 6;
    const int gend = (ITOT64 * (kblk + 1)) >> 6;

    // locate starting segment
    int it = 0, pre = 0;
    while (pre + (80 - (it << 2)) <= gbeg) { pre += 80 - (it << 2); ++it; }
    int li = gbeg - pre;

    // LDS: chunk(row, slot) = row*8 + slot, 16 B/chunk; slot = g ^ (row&7)
    __shared__ __align__(16) ushort_t A_s[2048 * 8];   // 32 KB (256 rows x 8 granules)
    __shared__ __align__(16) ushort_t B_s[2048 * 8];   // 32 KB

    const int t    = threadIdx.x;            // 0..511
    const int lane = t & 63;
    const int wid  = t >> 6;                 // 0..7
    const int wm   = (wid >> 1) * 64;        // 0,64,128,192
    const int wn   = (wid & 1) * 128;        // 0,128
    const int l16  = lane & 15;
    const int qk   = lane >> 4;              // k-quad within a 32-K MFMA step

    // ---- DMA lane constants (8 lanes/row: each 16-lane phase = 2 full lines)
    uint32_t offA[4], offB[4];
    #pragma unroll
    for (int j = 0; j < 4; ++j) {
        const int c = (wid << 8) + (j << 6) + lane;   // chunk 0..2047
        const int row = c >> 3;
        const int g = (c & 7) ^ (row & 7);
        offA[j] = (uint32_t)row * LC + (g << 3);
        offB[j] = (uint32_t)(bn0 + row) * LC + (g << 3);
    }

    // ---- LDS fragment read byte-addresses (loop-invariant)
    int adrA[2][4], adrB[2][8];
    #pragma unroll
    for (int step = 0; step < 2; ++step) {
        const int kf = step * 4 + qk;        // granule 0..7
        #pragma unroll
        for (int mt = 0; mt < 4; ++mt) {
            const int r = wm + mt * 16 + l16;
            adrA[step][mt] = ((r << 3) + (kf ^ (r & 7))) << 4;
        }
        #pragma unroll
        for (int nt = 0; nt < 8; ++nt) {
            const int r = wn + nt * 16 + l16;
            adrB[step][nt] = ((r << 3) + (kf ^ (r & 7))) << 4;
        }
    }

    int   i0    = it << 8;                   // 256*it
    int   k0    = i0 + (li << 6);            // kstart + li*64
    size_t baseA = (size_t)i0 * LC + k0;

    float4v acc[4][8];
    #pragma unroll
    for (int mt = 0; mt < 4; ++mt)
        #pragma unroll
        for (int nt = 0; nt < 8; ++nt)
            #pragma unroll
            for (int r = 0; r < 4; ++r) acc[mt][nt][r] = 0.f;

    for (int g = gbeg; g < gend; ++g) {
        __syncthreads();                     // prior fragment reads done
        #pragma unroll
        for (int j = 0; j < 4; ++j)
            load_lds16(Tb + baseA + offA[j], A_s + (((wid << 8) + (j << 6)) << 3));
        #pragma unroll
        for (int j = 0; j < 4; ++j)
            load_lds16(Xb + k0 + offB[j],   B_s + (((wid << 8) + (j << 6)) << 3));
        __syncthreads();                     // DMA drained (vmcnt 0 at barrier)

        #pragma unroll
        for (int step = 0; step < 2; ++step) {
            short8 af[4], bfr[8];
            #pragma unroll
            for (int mt = 0; mt < 4; ++mt)
                af[mt] = *(const short8*)((const char*)A_s + adrA[step][mt]);
            #pragma unroll
            for (int nt = 0; nt < 8; ++nt)
                bfr[nt] = *(const short8*)((const char*)B_s + adrB[step][nt]);
            #pragma unroll
            for (int mt = 0; mt < 4; ++mt)
                #pragma unroll
                for (int nt = 0; nt < 8; ++nt)
                    acc[mt][nt] = __builtin_amdgcn_mfma_f32_16x16x32_bf16(
                        af[mt], bfr[nt], acc[mt][nt], 0, 0, 0);
        }

        ++li;
        const bool segEnd = (li == 80 - (it << 2));
        if (segEnd || g + 1 == gend) {
            // epilogue flush: out[b] += sum_i x[b,i] * D[i,b], x from bf16 Xb
            #pragma unroll
            for (int nt = 0; nt < 8; ++nt) {
                const int b = bn0 + wn + nt * 16 + l16;
                const ushort_t* xb = Xb + (size_t)b * LC + i0 + wm + qk * 4;
                float s = 0.f;
                #pragma unroll
                for (int mt = 0; mt < 4; ++mt) {
                    ushort4 xv = *(const ushort4*)(xb + mt * 16);
                    s += acc[mt][nt][0] * bf16_to_f32(xv.x)
                       + acc[mt][nt][1] * bf16_to_f32(xv.y)
                       + acc[mt][nt][2] * bf16_to_f32(xv.z)
                       + acc[mt][nt][3] * bf16_to_f32(xv.w);
                }
                s += __shfl_xor(s, 16);      // reduce the 4 k-quads (same b)
                s += __shfl_xor(s, 32);
                if (qk == 0) atomicAdd(&out[b], s);
            }
            #pragma unroll
            for (int mt = 0; mt < 4; ++mt)
                #pragma unroll
                for (int nt = 0; nt < 8; ++nt)
                    #pragma unroll
                    for (int r = 0; r < 4; ++r) acc[mt][nt][r] = 0.f;
        }
        if (segEnd) {
            ++it; li = 0;
            if (it < 20) {
                i0 = it << 8;
                k0 = i0;
                baseA = (size_t)i0 * LC + k0;
            }
        } else {
            k0 += 64;
            baseA += 64;
        }
    }
}

// ===========================================================================
// Fallback (ws too small): proven R2 path, fp32 staging from global.
// ===========================================================================
__global__ __launch_bounds__(256) void init_kernel(
    const float* __restrict__ x, const float* __restrict__ th0,
    const float* __restrict__ thlc, float* __restrict__ out)
{
    const int b = blockIdx.x;
    const float4* xb = (const float4*)(x + (size_t)b * LC);
    const float4* tv = (const float4*)thlc;
    float s = 0.f;
    for (int i = threadIdx.x; i < LC / 4; i += 256) {
        float4 a = xb[i], t = tv[i];
        s += a.x * t.x + a.y * t.y + a.z * t.z + a.w * t.w;
    }
    s += __shfl_xor(s, 1);  s += __shfl_xor(s, 2);  s += __shfl_xor(s, 4);
    s += __shfl_xor(s, 8);  s += __shfl_xor(s, 16); s += __shfl_xor(s, 32);
    __shared__ float red[4];
    if ((threadIdx.x & 63) == 0) red[threadIdx.x >> 6] = s;
    __syncthreads();
    if (threadIdx.x == 0) out[b] = th0[0] + red[0] + red[1] + red[2] + red[3];
}

__global__ __launch_bounds__(256) void pair_kernel(
    const float* __restrict__ T, const float* __restrict__ X,
    float* __restrict__ out)
{
    const int n  = blockIdx.x;
    const int r  = n & 7;
    const int g  = n >> 3;
    const int i0  = (g >> 3) * 128;
    const int bn0 = (g & 7) * 128;
    const int kstart = i0;
    const int nIter  = (LC - kstart) >> 6;
    const int ipc    = (nIter + 7) >> 3;
    const int itBeg  = r * ipc;
    const int itEnd  = (itBeg + ipc < nIter) ? (itBeg + ipc) : nIter;
    if (itBeg >= itEnd) return;
    const int kbeg   = kstart + (itBeg << 6);

    __shared__ __align__(16) short A_s[8 * 128 * 8];
    __shared__ __align__(16) short B_s[8 * 128 * 8];

    const int t    = threadIdx.x;
    const int lane = t & 63;
    const int wid  = t >> 6;
    const int wm   = (wid >> 1) * 64;
    const int wn   = (wid & 1) * 64;
    const int l16  = lane & 15;
    const int qk   = lane >> 4;

    const float* pA[4]; const float* pB[4]; int sIdx[4];
    #pragma unroll
    for (int u = 0; u < 4; ++u) {
        const int id  = t + u * 256;
        const int row = id >> 3;
        const int kq  = id & 7;
        pA[u] = T + (size_t)(i0 + row) * LC + kbeg + kq * 8;
        pB[u] = X + (size_t)(bn0 + row) * LC + kbeg + kq * 8;
        sIdx[u] = (kq * 128 + (row ^ kq)) * 8;
    }

    float4v acc[4][4] = {};
    for (int itr = itBeg; itr < itEnd; ++itr) {
        __syncthreads();
        #pragma unroll
        for (int u = 0; u < 4; ++u) {
            float4 a0 = ((const float4*)pA[u])[0];
            float4 a1 = ((const float4*)pA[u])[1];
            float4 b0 = ((const float4*)pB[u])[0];
            float4 b1 = ((const float4*)pB[u])[1];
            pA[u] += 64; pB[u] += 64;
            uint4v va, vb;
            va[0] = pack_bf16x2(a0.x, a0.y); va[1] = pack_bf16x2(a0.z, a0.w);
            va[2] = pack_bf16x2(a1.x, a1.y); va[3] = pack_bf16x2(a1.z, a1.w);
            vb[0] = pack_bf16x2(b0.x, b0.y); vb[1] = pack_bf16x2(b0.z, b0.w);
            vb[2] = pack_bf16x2(b1.x, b1.y); vb[3] = pack_bf16x2(b1.z, b1.w);
            *(uint4v*)(A_s + sIdx[u]) = va;
            *(uint4v*)(B_s + sIdx[u]) = vb;
        }
        __syncthreads();
        #pragma unroll
        for (int step = 0; step < 2; ++step) {
            const int kf = step * 4 + qk;
            short8 af[4], bfr[4];
            #pragma unroll
            for (int mt = 0; mt < 4; ++mt)
                af[mt] = *(const short8*)(A_s + (kf * 128 + ((wm + mt * 16 + l16) ^ kf)) * 8);
            #pragma unroll
            for (int nt = 0; nt < 4; ++nt)
                bfr[nt] = *(const short8*)(B_s + (kf * 128 + ((wn + nt * 16 + l16) ^ kf)) * 8);
            #pragma unroll
            for (int mt = 0; mt < 4; ++mt)
                #pragma unroll
                for (int nt = 0; nt < 4; ++nt)
                    acc[mt][nt] = __builtin_amdgcn_mfma_f32_16x16x32_bf16(
                        af[mt], bfr[nt], acc[mt][nt], 0, 0, 0);
        }
    }
    #pragma unroll
    for (int nt = 0; nt < 4; ++nt) {
        const int b = bn0 + wn + nt * 16 + l16;
        const float* xb = X + (size_t)b * LC + i0 + wm + qk * 4;
        float s = 0.f;
        #pragma unroll
        for (int mt = 0; mt < 4; ++mt) {
            float4 xv = *(const float4*)(xb + mt * 16);
            s += acc[mt][nt][0] * xv.x + acc[mt][nt][1] * xv.y +
                 acc[mt][nt][2] * xv.z + acc[mt][nt][3] * xv.w;
        }
        s += __shfl_xor(s, 16);
        s += __shfl_xor(s, 32);
        if (qk == 0) atomicAdd(&out[b], s);
    }
}

extern "C" void kernel_launch(void* const* d_in, const int* in_sizes, int n_in,
                              void* d_out, int out_size, void* d_ws, size_t ws_size,
                              hipStream_t stream) {
    const float* x    = (const float*)d_in[0];   // (B, L, C) fp32
    const float* th0  = (const float*)d_in[1];   // (1,)
    const float* thlc = (const float*)d_in[2];   // (1, L, C)
    const float* T    = (const float*)d_in[3];   // (1, L, C, L, C) — pre-masked
    float* out = (float*)d_out;                  // (B, 1) fp32

    if (ws_size >= WS_NEED) {
        ushort_t* Tb = (ushort_t*)d_ws;
        ushort_t* Xb = (ushort_t*)((char*)d_ws + TB_BYTES);
        conv_kernel<<<LC + NB, 256, 0, stream>>>(T, x, th0, thlc, Tb, Xb, out);
        pair_bf<<<256, 512, 0, stream>>>(Tb, Xb, out);
    } else {
        init_kernel<<<NB, 256, 0, stream>>>(x, th0, thlc, out);
        pair_kernel<<<(LC / 128) * (NB / 128) * 8, 256, 0, stream>>>(T, x, out);
    }
}

// Round 8
// 217.553 us; speedup vs baseline: 1.0290x; 1.0181x over previous
//
#include <hip/hip_runtime.h>
#include <stdint.h>

// Problem constants
#define LDIM 256
#define CDIM 20
#define LC   5120      // L*C
#define NB   1024      // batch
#define BM   256       // i-tile rows
#define BN   256       // batch tile
#define ITOT64 840     // sum_it (80 - 4*it), it=0..19 : 64-K iters per b-col
// exact identities (BM=256): kstart(it) = 256*it = i0 ; iters64(it) = 80 - 4*it

typedef __attribute__((ext_vector_type(8))) short short8;       // 8 bf16 (4 VGPR)
typedef __attribute__((ext_vector_type(4))) float float4v;      // MFMA acc
typedef __attribute__((ext_vector_type(4))) unsigned int uint4v;
typedef unsigned short ushort_t;

#define TB_BYTES (52428800ull)            // 5120*5120*2
#define XB_BYTES (10485760ull)            // 1024*5120*2
#define WS_NEED  (TB_BYTES + XB_BYTES)

// round-to-nearest-even fp32 -> bf16, packed pair
__device__ inline uint32_t pack_bf16x2(float a, float b) {
    uint32_t ua = __float_as_uint(a);
    uint32_t ub = __float_as_uint(b);
    ua += 0x7fffu + ((ua >> 16) & 1u);
    ub += 0x7fffu + ((ub >> 16) & 1u);
    return (ua >> 16) | (ub & 0xffff0000u);
}

__device__ inline float bf16_to_f32(ushort_t u) {
    return __uint_as_float(((uint32_t)u) << 16);
}

// async global->LDS 16B; lds base wave-uniform (HW: base + lane*16). aux=0:
// R6 showed NT (aux=2) wrecks staging BW.
__device__ inline void load_lds16(const void* g, void* l) {
    __builtin_amdgcn_global_load_lds(
        (const __attribute__((address_space(1))) uint32_t*)g,
        (__attribute__((address_space(3))) uint32_t*)l, 16, 0, 0);
}

// ---------------------------------------------------------------------------
// Convert pass: T fp32 -> bf16 (cols >= BM-tile kstart only), X fp32 -> bf16,
// fused out[b] = theta0 + dot(theta_lc, x[b,:]).
// ---------------------------------------------------------------------------
__global__ __launch_bounds__(256) void conv_kernel(
    const float* __restrict__ T, const float* __restrict__ X,
    const float* __restrict__ th0, const float* __restrict__ thlc,
    ushort_t* __restrict__ Tb, ushort_t* __restrict__ Xb,
    float* __restrict__ out)
{
    const int bid = blockIdx.x;
    const int t   = threadIdx.x;
    __shared__ float red[4];

    if (bid < LC) {
        const int r  = bid;
        const int tk = (r >> 8) << 8;      // BM=256 tile kstart (exact identity)
        const float*  src = T  + (size_t)r * LC;
        ushort_t*     dst = Tb + (size_t)r * LC;
        for (int c = tk + t * 4; c < LC; c += 1024) {
            float4 f = *(const float4*)(src + c);
            uint2 u;
            u.x = pack_bf16x2(f.x, f.y);
            u.y = pack_bf16x2(f.z, f.w);
            *(uint2*)(dst + c) = u;
        }
    } else {
        const int b = bid - LC;
        const float*  src = X  + (size_t)b * LC;
        ushort_t*     dst = Xb + (size_t)b * LC;
        float s = 0.f;
        for (int c = t * 4; c < LC; c += 1024) {
            float4 f = *(const float4*)(src + c);
            float4 w = *(const float4*)(thlc + c);
            s += f.x * w.x + f.y * w.y + f.z * w.z + f.w * w.w;
            uint2 u;
            u.x = pack_bf16x2(f.x, f.y);
            u.y = pack_bf16x2(f.z, f.w);
            *(uint2*)(dst + c) = u;
        }
        s += __shfl_xor(s, 1);  s += __shfl_xor(s, 2);  s += __shfl_xor(s, 4);
        s += __shfl_xor(s, 8);  s += __shfl_xor(s, 16); s += __shfl_xor(s, 32);
        if ((t & 63) == 0) red[t >> 6] = s;
        __syncthreads();
        if (t == 0) out[b] = th0[0] + red[0] + red[1] + red[2] + red[3];
    }
}

// ---------------------------------------------------------------------------
// Pair kernel v7: 256x256 tile, 512 threads (8 waves, 64x128 per wave),
// BK=64, EXPLICIT LDS DOUBLE-BUFFER (2 x 64 KB = 128 KB of gfx950's 160 KB),
// full-line DMA, R5-proven decode. 256 blocks, 1/CU; within-block dbuf
// restores the DMA/compute overlap that 1-resident-block lost in R7.
// Staged bytes: 215 MB.
// ---------------------------------------------------------------------------
__global__ __launch_bounds__(512, 2) void pair_bf(
    const ushort_t* __restrict__ Tb, const ushort_t* __restrict__ Xb,
    float* __restrict__ out)
{
    const int n    = blockIdx.x;                   // 0..255
    const int kblk = (n & 7) | ((n >> 5) << 3);    // 0..63; siblings n,n+8,n+16,n+24
    const int bn0  = ((n >> 3) & 3) * BN;

    const int gbeg = (ITOT64 * kblk) >> 6;
    const int gend = (ITOT64 * (kblk + 1)) >> 6;

    // locate starting segment
    int it = 0, pre = 0;
    while (pre + (80 - (it << 2)) <= gbeg) { pre += 80 - (it << 2); ++it; }
    const int li = gbeg - pre;

    // LDS double-buffered: chunk(row, slot) = row*8 + slot, 16 B/chunk;
    // slot = granule ^ (row&7)
    __shared__ __align__(16) ushort_t A_s[2][2048 * 8];   // 2 x 32 KB
    __shared__ __align__(16) ushort_t B_s[2][2048 * 8];   // 2 x 32 KB

    const int t    = threadIdx.x;            // 0..511
    const int lane = t & 63;
    const int wid  = t >> 6;                 // 0..7
    const int wm   = (wid >> 1) * 64;        // 0,64,128,192
    const int wn   = (wid & 1) * 128;        // 0,128
    const int l16  = lane & 15;
    const int qk   = lane >> 4;              // k-quad within a 32-K MFMA step

    // ---- DMA lane constants (8 lanes/row: each 16-lane phase = 2 full lines)
    uint32_t offA[4], offB[4];
    #pragma unroll
    for (int j = 0; j < 4; ++j) {
        const int c = (wid << 8) + (j << 6) + lane;   // chunk 0..2047
        const int row = c >> 3;
        const int g = (c & 7) ^ (row & 7);
        offA[j] = (uint32_t)row * LC + (g << 3);
        offB[j] = (uint32_t)(bn0 + row) * LC + (g << 3);
    }

    // ---- LDS fragment read byte-addresses (loop-invariant)
    int adrA[2][4], adrB[2][8];
    #pragma unroll
    for (int step = 0; step < 2; ++step) {
        const int kf = step * 4 + qk;        // granule 0..7
        #pragma unroll
        for (int mt = 0; mt < 4; ++mt) {
            const int r = wm + mt * 16 + l16;
            adrA[step][mt] = ((r << 3) + (kf ^ (r & 7))) << 4;
        }
        #pragma unroll
        for (int nt = 0; nt < 8; ++nt) {
            const int r = wn + nt * 16 + l16;
            adrB[step][nt] = ((r << 3) + (kf ^ (r & 7))) << 4;
        }
    }

    // ---- issue-side pipeline state (1 iter ahead of compute) --------------
    int itI = it, liI = li;
    int k0; size_t baseA;
    auto rebaseI = [&]() {
        const int i0I = itI << 8;
        k0    = i0I + (liI << 6);
        baseA = (size_t)i0I * LC + k0;
    };
    rebaseI();
    auto issue = [&](int cb) {
        #pragma unroll
        for (int j = 0; j < 4; ++j)
            load_lds16(Tb + baseA + offA[j], A_s[cb] + (((wid << 8) + (j << 6)) << 3));
        #pragma unroll
        for (int j = 0; j < 4; ++j)
            load_lds16(Xb + k0 + offB[j],   B_s[cb] + (((wid << 8) + (j << 6)) << 3));
        // advance issue state
        ++liI;
        if (liI == 80 - (itI << 2)) {
            ++itI; liI = 0;
            if (itI < 20) rebaseI();
        } else { k0 += 64; baseA += 64; }
    };

    float4v acc[4][8];
    #pragma unroll
    for (int mt = 0; mt < 4; ++mt)
        #pragma unroll
        for (int nt = 0; nt < 8; ++nt)
            #pragma unroll
            for (int r = 0; r < 4; ++r) acc[mt][nt][r] = 0.f;

    // compute-side segment state
    int itC = it, liC = li;

    issue(0);                                // prefetch first stage into buf 0

    for (int g = gbeg; g < gend; ++g) {
        const int cur = (g - gbeg) & 1;
        __syncthreads();                     // drains iter g's DMA (had compute(g-1) to fly)
        if (g + 1 < gend) issue(cur ^ 1);    // prefetch g+1 into the other buffer

        // compute from buf[cur]
        {
            const ushort_t* As = A_s[cur];
            const ushort_t* Bs = B_s[cur];
            #pragma unroll
            for (int step = 0; step < 2; ++step) {
                short8 af[4], bfr[8];
                #pragma unroll
                for (int mt = 0; mt < 4; ++mt)
                    af[mt] = *(const short8*)((const char*)As + adrA[step][mt]);
                #pragma unroll
                for (int nt = 0; nt < 8; ++nt)
                    bfr[nt] = *(const short8*)((const char*)Bs + adrB[step][nt]);
                #pragma unroll
                for (int mt = 0; mt < 4; ++mt)
                    #pragma unroll
                    for (int nt = 0; nt < 8; ++nt)
                        acc[mt][nt] = __builtin_amdgcn_mfma_f32_16x16x32_bf16(
                            af[mt], bfr[nt], acc[mt][nt], 0, 0, 0);
            }
        }

        ++liC;
        const bool segEnd = (liC == 80 - (itC << 2));
        if (segEnd || g + 1 == gend) {
            // epilogue flush: out[b] += sum_i x[b,i] * D[i,b], x from bf16 Xb
            const int i0 = itC << 8;
            #pragma unroll
            for (int nt = 0; nt < 8; ++nt) {
                const int b = bn0 + wn + nt * 16 + l16;
                const ushort_t* xb = Xb + (size_t)b * LC + i0 + wm + qk * 4;
                float s = 0.f;
                #pragma unroll
                for (int mt = 0; mt < 4; ++mt) {
                    ushort4 xv = *(const ushort4*)(xb + mt * 16);
                    s += acc[mt][nt][0] * bf16_to_f32(xv.x)
                       + acc[mt][nt][1] * bf16_to_f32(xv.y)
                       + acc[mt][nt][2] * bf16_to_f32(xv.z)
                       + acc[mt][nt][3] * bf16_to_f32(xv.w);
                }
                s += __shfl_xor(s, 16);      // reduce the 4 k-quads (same b)
                s += __shfl_xor(s, 32);
                if (qk == 0) atomicAdd(&out[b], s);
            }
            #pragma unroll
            for (int mt = 0; mt < 4; ++mt)
                #pragma unroll
                for (int nt = 0; nt < 8; ++nt)
                    #pragma unroll
                    for (int r = 0; r < 4; ++r) acc[mt][nt][r] = 0.f;
        }
        if (segEnd) { ++itC; liC = 0; }
    }
}

// ===========================================================================
// Fallback (ws too small): proven R2 path, fp32 staging from global.
// ===========================================================================
__global__ __launch_bounds__(256) void init_kernel(
    const float* __restrict__ x, const float* __restrict__ th0,
    const float* __restrict__ thlc, float* __restrict__ out)
{
    const int b = blockIdx.x;
    const float4* xb = (const float4*)(x + (size_t)b * LC);
    const float4* tv = (const float4*)thlc;
    float s = 0.f;
    for (int i = threadIdx.x; i < LC / 4; i += 256) {
        float4 a = xb[i], t = tv[i];
        s += a.x * t.x + a.y * t.y + a.z * t.z + a.w * t.w;
    }
    s += __shfl_xor(s, 1);  s += __shfl_xor(s, 2);  s += __shfl_xor(s, 4);
    s += __shfl_xor(s, 8);  s += __shfl_xor(s, 16); s += __shfl_xor(s, 32);
    __shared__ float red[4];
    if ((threadIdx.x & 63) == 0) red[threadIdx.x >> 6] = s;
    __syncthreads();
    if (threadIdx.x == 0) out[b] = th0[0] + red[0] + red[1] + red[2] + red[3];
}

__global__ __launch_bounds__(256) void pair_kernel(
    const float* __restrict__ T, const float* __restrict__ X,
    float* __restrict__ out)
{
    const int n  = blockIdx.x;
    const int r  = n & 7;
    const int g  = n >> 3;
    const int i0  = (g >> 3) * 128;
    const int bn0 = (g & 7) * 128;
    const int kstart = i0;
    const int nIter  = (LC - kstart) >> 6;
    const int ipc    = (nIter + 7) >> 3;
    const int itBeg  = r * ipc;
    const int itEnd  = (itBeg + ipc < nIter) ? (itBeg + ipc) : nIter;
    if (itBeg >= itEnd) return;
    const int kbeg   = kstart + (itBeg << 6);

    __shared__ __align__(16) short A_s[8 * 128 * 8];
    __shared__ __align__(16) short B_s[8 * 128 * 8];

    const int t    = threadIdx.x;
    const int lane = t & 63;
    const int wid  = t >> 6;
    const int wm   = (wid >> 1) * 64;
    const int wn   = (wid & 1) * 64;
    const int l16  = lane & 15;
    const int qk   = lane >> 4;

    const float* pA[4]; const float* pB[4]; int sIdx[4];
    #pragma unroll
    for (int u = 0; u < 4; ++u) {
        const int id  = t + u * 256;
        const int row = id >> 3;
        const int kq  = id & 7;
        pA[u] = T + (size_t)(i0 + row) * LC + kbeg + kq * 8;
        pB[u] = X + (size_t)(bn0 + row) * LC + kbeg + kq * 8;
        sIdx[u] = (kq * 128 + (row ^ kq)) * 8;
    }

    float4v acc[4][4] = {};
    for (int itr = itBeg; itr < itEnd; ++itr) {
        __syncthreads();
        #pragma unroll
        for (int u = 0; u < 4; ++u) {
            float4 a0 = ((const float4*)pA[u])[0];
            float4 a1 = ((const float4*)pA[u])[1];
            float4 b0 = ((const float4*)pB[u])[0];
            float4 b1 = ((const float4*)pB[u])[1];
            pA[u] += 64; pB[u] += 64;
            uint4v va, vb;
            va[0] = pack_bf16x2(a0.x, a0.y); va[1] = pack_bf16x2(a0.z, a0.w);
            va[2] = pack_bf16x2(a1.x, a1.y); va[3] = pack_bf16x2(a1.z, a1.w);
            vb[0] = pack_bf16x2(b0.x, b0.y); vb[1] = pack_bf16x2(b0.z, b0.w);
            vb[2] = pack_bf16x2(b1.x, b1.y); vb[3] = pack_bf16x2(b1.z, b1.w);
            *(uint4v*)(A_s + sIdx[u]) = va;
            *(uint4v*)(B_s + sIdx[u]) = vb;
        }
        __syncthreads();
        #pragma unroll
        for (int step = 0; step < 2; ++step) {
            const int kf = step * 4 + qk;
            short8 af[4], bfr[4];
            #pragma unroll
            for (int mt = 0; mt < 4; ++mt)
                af[mt] = *(const short8*)(A_s + (kf * 128 + ((wm + mt * 16 + l16) ^ kf)) * 8);
            #pragma unroll
            for (int nt = 0; nt < 4; ++nt)
                bfr[nt] = *(const short8*)(B_s + (kf * 128 + ((wn + nt * 16 + l16) ^ kf)) * 8);
            #pragma unroll
            for (int mt = 0; mt < 4; ++mt)
                #pragma unroll
                for (int nt = 0; nt < 4; ++nt)
                    acc[mt][nt] = __builtin_amdgcn_mfma_f32_16x16x32_bf16(
                        af[mt], bfr[nt], acc[mt][nt], 0, 0, 0);
        }
    }
    #pragma unroll
    for (int nt = 0; nt < 4; ++nt) {
        const int b = bn0 + wn + nt * 16 + l16;
        const float* xb = X + (size_t)b * LC + i0 + wm + qk * 4;
        float s = 0.f;
        #pragma unroll
        for (int mt = 0; mt < 4; ++mt) {
            float4 xv = *(const float4*)(xb + mt * 16);
            s += acc[mt][nt][0] * xv.x + acc[mt][nt][1] * xv.y +
                 acc[mt][nt][2] * xv.z + acc[mt][nt][3] * xv.w;
        }
        s += __shfl_xor(s, 16);
        s += __shfl_xor(s, 32);
        if (qk == 0) atomicAdd(&out[b], s);
    }
}

extern "C" void kernel_launch(void* const* d_in, const int* in_sizes, int n_in,
                              void* d_out, int out_size, void* d_ws, size_t ws_size,
                              hipStream_t stream) {
    const float* x    = (const float*)d_in[0];   // (B, L, C) fp32
    const float* th0  = (const float*)d_in[1];   // (1,)
    const float* thlc = (const float*)d_in[2];   // (1, L, C)
    const float* T    = (const float*)d_in[3];   // (1, L, C, L, C) — pre-masked
    float* out = (float*)d_out;                  // (B, 1) fp32

    if (ws_size >= WS_NEED) {
        ushort_t* Tb = (ushort_t*)d_ws;
        ushort_t* Xb = (ushort_t*)((char*)d_ws + TB_BYTES);
        conv_kernel<<<LC + NB, 256, 0, stream>>>(T, x, th0, thlc, Tb, Xb, out);
        pair_bf<<<256, 512, 0, stream>>>(Tb, Xb, out);
    } else {
        init_kernel<<<NB, 256, 0, stream>>>(x, th0, thlc, out);
        pair_kernel<<<(LC / 128) * (NB / 128) * 8, 256, 0, stream>>>(T, x, out);
    }
}